// Round 1
// baseline (200.851 us; speedup 1.0000x reference)
//
#include <hip/hip_runtime.h>
#include <math.h>

// log(2*pi) + 1
#define LOG_2PI_PLUS_1 2.8378770664093454835606594728112

// Grid-stride masked log-sum reduction.
// Reads x as float4 (input is 4096*8192 fp32, divisible by 4, 16B-aligned from
// the harness allocator). Each lane accumulates in double; 64-lane shuffle
// reduce; cross-wave LDS reduce; one fp64 atomicAdd per block into ws[0].
__global__ __launch_bounds__(256) void masked_logsum_kernel(
    const float* __restrict__ x, long long n, double* __restrict__ ws) {
  const long long n4 = n >> 2;
  const float4* __restrict__ x4 = (const float4*)x;
  long long tid = (long long)blockIdx.x * blockDim.x + threadIdx.x;
  long long stride = (long long)gridDim.x * blockDim.x;

  double acc = 0.0;
  for (long long i = tid; i < n4; i += stride) {
    float4 v = x4[i];
    // sum the 4 lanes in float first (error negligible vs 2% tolerance on a
    // 3e7-magnitude total), then widen once to double.
    float s = 0.0f;
    s += (v.x != 0.0f) ? __logf(v.x) : 0.0f;
    s += (v.y != 0.0f) ? __logf(v.y) : 0.0f;
    s += (v.z != 0.0f) ? __logf(v.z) : 0.0f;
    s += (v.w != 0.0f) ? __logf(v.w) : 0.0f;
    acc += (double)s;
  }

  // tail (n not divisible by 4) — handled by global thread 0 only
  if (tid == 0) {
    for (long long i = n4 << 2; i < n; ++i) {
      float v = x[i];
      acc += (double)((v != 0.0f) ? __logf(v) : 0.0f);
    }
  }

  // 64-lane wave reduction (wave64!)
  #pragma unroll
  for (int off = 32; off > 0; off >>= 1) {
    acc += __shfl_down(acc, off, 64);
  }

  __shared__ double smem[4];  // 256 threads / 64 = 4 waves
  const int lane = threadIdx.x & 63;
  const int wave = threadIdx.x >> 6;
  if (lane == 0) smem[wave] = acc;
  __syncthreads();
  if (threadIdx.x == 0) {
    double t = smem[0] + smem[1] + smem[2] + smem[3];
    atomicAdd(ws, t);  // device-scope fp64 atomic (HW on gfx950)
  }
}

__global__ void finalize_kernel(const double* __restrict__ ws,
                                float* __restrict__ out, double mn_half) {
  double total = mn_half * LOG_2PI_PLUS_1 + 0.5 * ws[0];
  out[0] = (total > 0.0) ? (float)log1p(total) : 1.0f;
}

extern "C" void kernel_launch(void* const* d_in, const int* in_sizes, int n_in,
                              void* d_out, int out_size, void* d_ws, size_t ws_size,
                              hipStream_t stream) {
  const float* x = (const float*)d_in[0];
  long long n = (long long)in_sizes[0];
  double* ws = (double*)d_ws;

  // ws is re-poisoned to 0xAA before every timed launch — zero the accumulator.
  hipMemsetAsync(d_ws, 0, sizeof(double), stream);

  // 2048 blocks x 256 threads = 524288 threads; each handles 16 float4s.
  // Plenty of waves to hide HBM latency across 256 CUs.
  const int block = 256;
  const int grid = 2048;
  masked_logsum_kernel<<<grid, block, 0, stream>>>(x, n, ws);
  finalize_kernel<<<1, 1, 0, stream>>>(ws, (float*)d_out, 0.5 * (double)n);
}